// Round 1
// baseline (376.553 us; speedup 1.0000x reference)
//
#include <hip/hip_runtime.h>

static constexpr int NN   = 50000;    // nodes per batch
static constexpr int NBAT = 4;
static constexpr int NE   = 1600000;  // unique edges
static constexpr int NC   = 1000;
static constexpr int FN   = 64;
static constexpr int FCOL = 32;
static constexpr int HD   = 16;

// ---------- block reduction (256 threads, wave64) ----------
__device__ inline float block_reduce_256(float v) {
    __shared__ float s[4];
    int lane = threadIdx.x & 63, wid = threadIdx.x >> 6;
    #pragma unroll
    for (int o = 32; o > 0; o >>= 1) v += __shfl_down(v, o);
    if (lane == 0) s[wid] = v;
    __syncthreads();
    if (threadIdx.x == 0) {
        float t = 0.f;
        #pragma unroll
        for (int i = 0; i < 4; i++) t += s[i];
        return t;
    }
    return 0.f;
}

// ---------- degree count over dst ----------
__global__ void k_count(const int* __restrict__ dst, int* __restrict__ cnt) {
    int e = blockIdx.x * blockDim.x + threadIdx.x;
    if (e < NE) atomicAdd(&cnt[dst[e]], 1);
}

// deg = 4*cnt + 1 (B edge copies + self loop); dinv = rsqrt(deg). In-place int->float.
__global__ void k_dinv(float* __restrict__ buf) {
    int v = blockIdx.x * blockDim.x + threadIdx.x;
    if (v < NN) {
        int c = ((const int*)buf)[v];
        buf[v] = rsqrtf((float)(4 * c + 1));
    }
}

// ---------- y = x(batch0) @ W1  (no bias; bias added after aggregation) ----------
__global__ void k_xw1(const float* __restrict__ x, const float* __restrict__ W1,
                      float* __restrict__ y) {
    __shared__ float sW[FN * HD];
    for (int i = threadIdx.x; i < FN * HD; i += blockDim.x) sW[i] = W1[i];
    __syncthreads();
    int v = blockIdx.x * blockDim.x + threadIdx.x;
    if (v >= NN) return;
    const float4* xf = (const float4*)(x + (size_t)v * FN);
    float acc[HD];
    #pragma unroll
    for (int j = 0; j < HD; j++) acc[j] = 0.f;
    #pragma unroll
    for (int k4 = 0; k4 < FN / 4; k4++) {
        float4 f = xf[k4];
        #pragma unroll
        for (int j = 0; j < HD; j++) {
            acc[j] += f.x * sW[(4 * k4 + 0) * HD + j];
            acc[j] += f.y * sW[(4 * k4 + 1) * HD + j];
            acc[j] += f.z * sW[(4 * k4 + 2) * HD + j];
            acc[j] += f.w * sW[(4 * k4 + 3) * HD + j];
        }
    }
    float4* yp = (float4*)(y + (size_t)v * HD);
    #pragma unroll
    for (int q = 0; q < 4; q++)
        yp[q] = make_float4(acc[4*q], acc[4*q+1], acc[4*q+2], acc[4*q+3]);
}

// ---------- edge scatter: acc[d] += y[s] * 4*dinv[s]*dinv[d] ----------
// 16 consecutive threads handle one edge's 16 features (coalesced gather).
__global__ void k_scatter(const int* __restrict__ src, const int* __restrict__ dst,
                          const float* __restrict__ dinv, const float* __restrict__ y,
                          float* __restrict__ acc) {
    int gid = blockIdx.x * blockDim.x + threadIdx.x;   // < NE*16 = 25.6M
    int e = gid >> 4, j = gid & 15;
    if (e >= NE) return;
    int s = src[e], d = dst[e];
    float c = 4.f * dinv[s] * dinv[d];
    atomicAdd(&acc[d * HD + j], y[s * HD + j] * c);
}

// ---------- finalize conv1 (+bias, relu) then y2 = h1 @ W2, in place over y ----------
__global__ void k_fin1(const float* __restrict__ acc, float* __restrict__ y,
                       const float* __restrict__ dinv, const float* __restrict__ b1,
                       const float* __restrict__ W2) {
    __shared__ float sW[HD * HD];
    __shared__ float sb[HD];
    if (threadIdx.x < HD * HD) sW[threadIdx.x] = W2[threadIdx.x];
    if (threadIdx.x < HD) sb[threadIdx.x] = b1[threadIdx.x];
    __syncthreads();
    int v = blockIdx.x * blockDim.x + threadIdx.x;
    if (v >= NN) return;
    float dv = dinv[v], dv2 = dv * dv;
    const float4* ap = (const float4*)(acc + (size_t)v * HD);
    float4* yp = (float4*)(y + (size_t)v * HD);
    float a[HD];
    #pragma unroll
    for (int q = 0; q < 4; q++) {
        float4 av = ap[q]; float4 yv = yp[q];
        a[4*q+0] = fmaxf(av.x + yv.x * dv2 + sb[4*q+0], 0.f);
        a[4*q+1] = fmaxf(av.y + yv.y * dv2 + sb[4*q+1], 0.f);
        a[4*q+2] = fmaxf(av.z + yv.z * dv2 + sb[4*q+2], 0.f);
        a[4*q+3] = fmaxf(av.w + yv.w * dv2 + sb[4*q+3], 0.f);
    }
    float o[HD];
    #pragma unroll
    for (int k = 0; k < HD; k++) o[k] = 0.f;
    #pragma unroll
    for (int j = 0; j < HD; j++) {
        float aj = a[j];
        #pragma unroll
        for (int k = 0; k < HD; k++) o[k] += aj * sW[j * HD + k];
    }
    #pragma unroll
    for (int q = 0; q < 4; q++)
        yp[q] = make_float4(o[4*q], o[4*q+1], o[4*q+2], o[4*q+3]);
}

// ---------- finalize conv2 (+bias, relu), node_fc, reduce into sums[0] ----------
__global__ void k_fin2(const float* __restrict__ acc, const float* __restrict__ y,
                       const float* __restrict__ dinv, const float* __restrict__ b2,
                       const float* __restrict__ nfcW, const float* __restrict__ nfcb,
                       double* __restrict__ sums) {
    __shared__ float sb[HD], sw[HD];
    if (threadIdx.x < HD) { sb[threadIdx.x] = b2[threadIdx.x]; sw[threadIdx.x] = nfcW[threadIdx.x]; }
    __syncthreads();
    int v = blockIdx.x * blockDim.x + threadIdx.x;
    float sv = 0.f;
    if (v < NN) {
        float dv = dinv[v], dv2 = dv * dv;
        const float4* ap = (const float4*)(acc + (size_t)v * HD);
        const float4* yp = (const float4*)(y + (size_t)v * HD);
        sv = nfcb[0];
        #pragma unroll
        for (int q = 0; q < 4; q++) {
            float4 av = ap[q]; float4 yv = yp[q];
            sv += fmaxf(av.x + yv.x * dv2 + sb[4*q+0], 0.f) * sw[4*q+0];
            sv += fmaxf(av.y + yv.y * dv2 + sb[4*q+1], 0.f) * sw[4*q+1];
            sv += fmaxf(av.z + yv.z * dv2 + sb[4*q+2], 0.f) * sw[4*q+2];
            sv += fmaxf(av.w + yv.w * dv2 + sb[4*q+3], 0.f) * sw[4*q+3];
        }
    }
    float bs = block_reduce_256(sv);
    if (threadIdx.x == 0) atomicAdd(&sums[0], (double)bs);
}

// ---------- batches 1..3: pure per-node MLP + reduce ----------
__global__ void __launch_bounds__(256) k_mlp(const float* __restrict__ x,
        const float* __restrict__ W1, const float* __restrict__ b1,
        const float* __restrict__ W2, const float* __restrict__ b2,
        const float* __restrict__ nfcW, const float* __restrict__ nfcb,
        double* __restrict__ sums) {
    __shared__ float sW1[FN * HD];
    __shared__ float sW2[HD * HD];
    __shared__ float sb1[HD], sb2[HD], sw[HD];
    for (int i = threadIdx.x; i < FN * HD; i += blockDim.x) sW1[i] = W1[i];
    if (threadIdx.x < HD * HD) sW2[threadIdx.x] = W2[threadIdx.x];
    if (threadIdx.x < HD) {
        sb1[threadIdx.x] = b1[threadIdx.x];
        sb2[threadIdx.x] = b2[threadIdx.x];
        sw[threadIdx.x]  = nfcW[threadIdx.x];
    }
    __syncthreads();
    int b = blockIdx.y + 1;
    int n = blockIdx.x * blockDim.x + threadIdx.x;
    float sv = 0.f;
    if (n < NN) {
        const float4* xf = (const float4*)(x + ((size_t)b * NN + n) * FN);
        float t1[HD];
        #pragma unroll
        for (int j = 0; j < HD; j++) t1[j] = sb1[j];
        #pragma unroll
        for (int k4 = 0; k4 < FN / 4; k4++) {
            float4 f = xf[k4];
            #pragma unroll
            for (int j = 0; j < HD; j++) {
                t1[j] += f.x * sW1[(4 * k4 + 0) * HD + j];
                t1[j] += f.y * sW1[(4 * k4 + 1) * HD + j];
                t1[j] += f.z * sW1[(4 * k4 + 2) * HD + j];
                t1[j] += f.w * sW1[(4 * k4 + 3) * HD + j];
            }
        }
        float t2[HD];
        #pragma unroll
        for (int k = 0; k < HD; k++) t2[k] = sb2[k];
        #pragma unroll
        for (int j = 0; j < HD; j++) {
            float aj = fmaxf(t1[j], 0.f);
            #pragma unroll
            for (int k = 0; k < HD; k++) t2[k] += aj * sW2[j * HD + k];
        }
        sv = nfcb[0];
        #pragma unroll
        for (int k = 0; k < HD; k++) sv += fmaxf(t2[k], 0.f) * sw[k];
    }
    float bs = block_reduce_256(sv);
    if (threadIdx.x == 0) atomicAdd(&sums[b], (double)bs);
}

// ---------- col path: one block per batch ----------
__global__ void k_col(const float* __restrict__ col, const float* __restrict__ cW1,
                      const float* __restrict__ cb1, const float* __restrict__ cW2,
                      const float* __restrict__ cb2, double* __restrict__ sums) {
    __shared__ float sW1[FCOL * HD];
    __shared__ float sb1[HD], sw2[HD];
    for (int i = threadIdx.x; i < FCOL * HD; i += blockDim.x) sW1[i] = cW1[i];
    if (threadIdx.x < HD) { sb1[threadIdx.x] = cb1[threadIdx.x]; sw2[threadIdx.x] = cW2[threadIdx.x]; }
    __syncthreads();
    int b = blockIdx.x;
    float sv = 0.f;
    for (int c = threadIdx.x; c < NC; c += blockDim.x) {
        const float4* cf = (const float4*)(col + ((size_t)b * NC + c) * FCOL);
        float h[HD];
        #pragma unroll
        for (int j = 0; j < HD; j++) h[j] = sb1[j];
        #pragma unroll
        for (int k4 = 0; k4 < FCOL / 4; k4++) {
            float4 f = cf[k4];
            #pragma unroll
            for (int j = 0; j < HD; j++) {
                h[j] += f.x * sW1[(4 * k4 + 0) * HD + j];
                h[j] += f.y * sW1[(4 * k4 + 1) * HD + j];
                h[j] += f.z * sW1[(4 * k4 + 2) * HD + j];
                h[j] += f.w * sW1[(4 * k4 + 3) * HD + j];
            }
        }
        float co = cb2[0];
        #pragma unroll
        for (int j = 0; j < HD; j++) co += fmaxf(h[j], 0.f) * sw2[j];
        sv += co;
    }
    float bs = block_reduce_256(sv);
    if (threadIdx.x == 0) sums[4 + b] = (double)bs;
}

// ---------- final tiny head ----------
__global__ void k_final(const double* __restrict__ sums,
                        const float* __restrict__ fcW, const float* __restrict__ fcb,
                        const float* __restrict__ outW, const float* __restrict__ outb,
                        float* __restrict__ out) {
    int b = threadIdx.x;
    if (b < NBAT) {
        float na = (float)(sums[b] * (1.0 / NN));
        float ca = (float)(sums[4 + b] * (1.0 / NC));
        float o = outb[0];
        #pragma unroll
        for (int j = 0; j < HD; j++) {
            float z = fmaxf(na * fcW[j] + ca * fcW[HD + j] + fcb[j], 0.f);
            o += z * outW[j];
        }
        out[b] = o;
    }
}

extern "C" void kernel_launch(void* const* d_in, const int* in_sizes, int n_in,
                              void* d_out, int out_size, void* d_ws, size_t ws_size,
                              hipStream_t stream) {
    const float* x    = (const float*)d_in[0];
    const float* col  = (const float*)d_in[1];
    const int*   ei   = (const int*)d_in[2];
    const float* W1   = (const float*)d_in[3];
    const float* b1   = (const float*)d_in[4];
    const float* W2   = (const float*)d_in[5];
    const float* b2   = (const float*)d_in[6];
    const float* nfcW = (const float*)d_in[7];
    const float* nfcb = (const float*)d_in[8];
    const float* cW1  = (const float*)d_in[9];
    const float* cb1  = (const float*)d_in[10];
    const float* cW2  = (const float*)d_in[11];
    const float* cb2  = (const float*)d_in[12];
    const float* fcW  = (const float*)d_in[13];
    const float* fcb  = (const float*)d_in[14];
    const float* outW = (const float*)d_in[15];
    const float* outb = (const float*)d_in[16];
    float* out = (float*)d_out;

    char* ws = (char*)d_ws;
    float*  dinv = (float*)ws;                           // 50000 f (cnt first, then dinv)
    float*  y    = (float*)(ws + 200704);                // 800000 f (y1 then y2, in place)
    float*  acc  = (float*)(ws + 200704 + 3200000);      // 800000 f
    double* sums = (double*)(ws + 200704 + 6400000);     // [0..3]=node, [4..7]=col

    const int* src = ei;
    const int* dst = ei + NE;

    hipMemsetAsync(dinv, 0, NN * sizeof(int), stream);
    hipMemsetAsync(sums, 0, 8 * sizeof(double), stream);

    k_count<<<(NE + 255) / 256, 256, 0, stream>>>(dst, (int*)dinv);
    k_dinv<<<(NN + 255) / 256, 256, 0, stream>>>(dinv);
    k_xw1<<<(NN + 255) / 256, 256, 0, stream>>>(x, W1, y);

    hipMemsetAsync(acc, 0, NN * HD * sizeof(float), stream);
    k_scatter<<<(NE * HD + 255) / 256, 256, 0, stream>>>(src, dst, dinv, y, acc);
    k_fin1<<<(NN + 255) / 256, 256, 0, stream>>>(acc, y, dinv, b1, W2);

    hipMemsetAsync(acc, 0, NN * HD * sizeof(float), stream);
    k_scatter<<<(NE * HD + 255) / 256, 256, 0, stream>>>(src, dst, dinv, y, acc);
    k_fin2<<<(NN + 255) / 256, 256, 0, stream>>>(acc, y, dinv, b2, nfcW, nfcb, sums);

    dim3 gmlp((NN + 255) / 256, NBAT - 1);
    k_mlp<<<gmlp, 256, 0, stream>>>(x, W1, b1, W2, b2, nfcW, nfcb, sums);
    k_col<<<NBAT, 256, 0, stream>>>(col, cW1, cb1, cW2, cb2, sums);
    k_final<<<1, 64, 0, stream>>>(sums, fcW, fcb, outW, outb, out);
}

// Round 2
// 291.693 us; speedup vs baseline: 1.2909x; 1.2909x over previous
//
#include <hip/hip_runtime.h>

static constexpr int NN   = 50000;    // nodes per batch
static constexpr int NBAT = 4;
static constexpr int NE   = 1600000;  // unique edges
static constexpr int NC   = 1000;
static constexpr int FN   = 64;
static constexpr int FCOL = 32;
static constexpr int HD   = 16;

// ---------- block reduction (256 threads, wave64) ----------
__device__ inline float block_reduce_256(float v) {
    __shared__ float s[4];
    int lane = threadIdx.x & 63, wid = threadIdx.x >> 6;
    #pragma unroll
    for (int o = 32; o > 0; o >>= 1) v += __shfl_down(v, o);
    if (lane == 0) s[wid] = v;
    __syncthreads();
    if (threadIdx.x == 0) {
        float t = 0.f;
        #pragma unroll
        for (int i = 0; i < 4; i++) t += s[i];
        return t;
    }
    return 0.f;
}

// ---------- degree count over dst ----------
__global__ void k_count(const int* __restrict__ dst, int* __restrict__ cnt) {
    int e = blockIdx.x * blockDim.x + threadIdx.x;
    if (e < NE) atomicAdd(&cnt[dst[e]], 1);
}

// ---------- exclusive scan, stage 1: 49 blocks x 1024 elems ----------
__global__ void k_scan1(const int* __restrict__ cnt, int* __restrict__ part,
                        int* __restrict__ bsum) {
    __shared__ int s[256];
    int tid = threadIdx.x;
    int idx = blockIdx.x * 1024 + tid * 4;
    int t0 = (idx + 0 < NN) ? cnt[idx + 0] : 0;
    int t1 = (idx + 1 < NN) ? cnt[idx + 1] : 0;
    int t2 = (idx + 2 < NN) ? cnt[idx + 2] : 0;
    int t3 = (idx + 3 < NN) ? cnt[idx + 3] : 0;
    int T = t0 + t1 + t2 + t3;
    s[tid] = T;
    __syncthreads();
    for (int off = 1; off < 256; off <<= 1) {
        int v = (tid >= off) ? s[tid - off] : 0;
        __syncthreads();
        s[tid] += v;
        __syncthreads();
    }
    int excl = s[tid] - T;
    if (tid == 255) bsum[blockIdx.x] = s[255];
    if (idx + 0 < NN) part[idx + 0] = excl;
    if (idx + 1 < NN) part[idx + 1] = excl + t0;
    if (idx + 2 < NN) part[idx + 2] = excl + t0 + t1;
    if (idx + 3 < NN) part[idx + 3] = excl + t0 + t1 + t2;
}

// ---------- scan stage 2: exclusive scan of 49 block sums ----------
__global__ void k_scan2(int* __restrict__ bsum) {
    __shared__ int s[64];
    int tid = threadIdx.x;
    int v = (tid < 49) ? bsum[tid] : 0;
    s[tid] = v;
    __syncthreads();
    for (int off = 1; off < 64; off <<= 1) {
        int u = (tid >= off) ? s[tid - off] : 0;
        __syncthreads();
        s[tid] += u;
        __syncthreads();
    }
    if (tid < 49) bsum[tid] = s[tid] - v;
}

// ---------- scan stage 3: add block offsets; also dinv = rsqrt(4*cnt+1) ----------
__global__ void k_rowptr(const int* __restrict__ cnt, int* __restrict__ rowptr,
                         const int* __restrict__ bsum, float* __restrict__ dinv) {
    int v = blockIdx.x * blockDim.x + threadIdx.x;
    if (v < NN) {
        rowptr[v] += bsum[v >> 10];
        dinv[v] = rsqrtf((float)(4 * cnt[v] + 1));
    }
}

// ---------- CSR fill: csr[rowptr[d] + cursor[d]++] = src ----------
__global__ void k_fill(const int* __restrict__ src, const int* __restrict__ dst,
                       const int* __restrict__ rowptr, int* __restrict__ cursor,
                       int* __restrict__ csr) {
    int e = blockIdx.x * blockDim.x + threadIdx.x;
    if (e < NE) {
        int d = dst[e];
        int pos = rowptr[d] + atomicAdd(&cursor[d], 1);
        csr[pos] = src[e];
    }
}

// ---------- y1 = x(batch0) @ W1 (no bias) ----------
__global__ void k_xw1(const float* __restrict__ x, const float* __restrict__ W1,
                      float* __restrict__ y) {
    __shared__ float sW[FN * HD];
    for (int i = threadIdx.x; i < FN * HD; i += blockDim.x) sW[i] = W1[i];
    __syncthreads();
    int v = blockIdx.x * blockDim.x + threadIdx.x;
    if (v >= NN) return;
    const float4* xf = (const float4*)(x + (size_t)v * FN);
    float acc[HD];
    #pragma unroll
    for (int j = 0; j < HD; j++) acc[j] = 0.f;
    #pragma unroll
    for (int k4 = 0; k4 < FN / 4; k4++) {
        float4 f = xf[k4];
        #pragma unroll
        for (int j = 0; j < HD; j++) {
            acc[j] += f.x * sW[(4 * k4 + 0) * HD + j];
            acc[j] += f.y * sW[(4 * k4 + 1) * HD + j];
            acc[j] += f.z * sW[(4 * k4 + 2) * HD + j];
            acc[j] += f.w * sW[(4 * k4 + 3) * HD + j];
        }
    }
    float4* yp = (float4*)(y + (size_t)v * HD);
    #pragma unroll
    for (int q = 0; q < 4; q++)
        yp[q] = make_float4(acc[4*q], acc[4*q+1], acc[4*q+2], acc[4*q+3]);
}

// ---------- conv1 gather: h = relu(agg + b1); y2 = h @ W2 ----------
// 16 lanes per node; lane j owns feature j.
__global__ void __launch_bounds__(256) k_conv1(
        const int* __restrict__ rowptr, const int* __restrict__ cnt,
        const int* __restrict__ csr, const float* __restrict__ dinv,
        const float* __restrict__ y1, const float* __restrict__ b1,
        const float* __restrict__ W2, float* __restrict__ y2) {
    __shared__ float sW[HD * HD];
    __shared__ float sb[HD];
    if (threadIdx.x < HD * HD) sW[threadIdx.x] = W2[threadIdx.x];
    if (threadIdx.x < HD) sb[threadIdx.x] = b1[threadIdx.x];
    __syncthreads();
    int j = threadIdx.x & 15;
    int v = blockIdx.x * 16 + (threadIdx.x >> 4);
    float h = 0.f;
    if (v < NN) {
        int start = rowptr[v], n = cnt[v];
        float s = 0.f;
        int i = 0;
        for (; i + 2 <= n; i += 2) {
            int u0 = csr[start + i], u1 = csr[start + i + 1];
            s += dinv[u0] * y1[u0 * HD + j] + dinv[u1] * y1[u1 * HD + j];
        }
        if (i < n) { int u = csr[start + i]; s += dinv[u] * y1[u * HD + j]; }
        float dv = dinv[v];
        h = fmaxf(4.f * dv * s + dv * dv * y1[v * HD + j] + sb[j], 0.f);
    }
    int base = (threadIdx.x & 63) & 48;   // 16-group base within wave
    float o = 0.f;
    #pragma unroll
    for (int k = 0; k < HD; k++)
        o += __shfl(h, base + k) * sW[k * HD + j];
    if (v < NN) y2[v * HD + j] = o;
}

// ---------- conv2 gather + node_fc + mean-reduce into sums[0] ----------
__global__ void __launch_bounds__(256) k_conv2(
        const int* __restrict__ rowptr, const int* __restrict__ cnt,
        const int* __restrict__ csr, const float* __restrict__ dinv,
        const float* __restrict__ y2, const float* __restrict__ b2,
        const float* __restrict__ nfcW, const float* __restrict__ nfcb,
        double* __restrict__ sums) {
    __shared__ float sb[HD], sw[HD];
    if (threadIdx.x < HD) { sb[threadIdx.x] = b2[threadIdx.x]; sw[threadIdx.x] = nfcW[threadIdx.x]; }
    __syncthreads();
    int j = threadIdx.x & 15;
    int v = blockIdx.x * 16 + (threadIdx.x >> 4);
    float t = 0.f;
    if (v < NN) {
        int start = rowptr[v], n = cnt[v];
        float s = 0.f;
        int i = 0;
        for (; i + 2 <= n; i += 2) {
            int u0 = csr[start + i], u1 = csr[start + i + 1];
            s += dinv[u0] * y2[u0 * HD + j] + dinv[u1] * y2[u1 * HD + j];
        }
        if (i < n) { int u = csr[start + i]; s += dinv[u] * y2[u * HD + j]; }
        float dv = dinv[v];
        float h = fmaxf(4.f * dv * s + dv * dv * y2[v * HD + j] + sb[j], 0.f);
        t = h * sw[j];
    }
    t += __shfl_xor(t, 1);
    t += __shfl_xor(t, 2);
    t += __shfl_xor(t, 4);
    t += __shfl_xor(t, 8);
    float sv = (j == 0 && v < NN) ? (t + nfcb[0]) : 0.f;
    float bs = block_reduce_256(sv);
    if (threadIdx.x == 0) atomicAdd(&sums[0], (double)bs);
}

// ---------- batches 1..3: pure per-node MLP + reduce ----------
__global__ void __launch_bounds__(256) k_mlp(const float* __restrict__ x,
        const float* __restrict__ W1, const float* __restrict__ b1,
        const float* __restrict__ W2, const float* __restrict__ b2,
        const float* __restrict__ nfcW, const float* __restrict__ nfcb,
        double* __restrict__ sums) {
    __shared__ float sW1[FN * HD];
    __shared__ float sW2[HD * HD];
    __shared__ float sb1[HD], sb2[HD], sw[HD];
    for (int i = threadIdx.x; i < FN * HD; i += blockDim.x) sW1[i] = W1[i];
    if (threadIdx.x < HD * HD) sW2[threadIdx.x] = W2[threadIdx.x];
    if (threadIdx.x < HD) {
        sb1[threadIdx.x] = b1[threadIdx.x];
        sb2[threadIdx.x] = b2[threadIdx.x];
        sw[threadIdx.x]  = nfcW[threadIdx.x];
    }
    __syncthreads();
    int b = blockIdx.y + 1;
    int n = blockIdx.x * blockDim.x + threadIdx.x;
    float sv = 0.f;
    if (n < NN) {
        const float4* xf = (const float4*)(x + ((size_t)b * NN + n) * FN);
        float t1[HD];
        #pragma unroll
        for (int j = 0; j < HD; j++) t1[j] = sb1[j];
        #pragma unroll
        for (int k4 = 0; k4 < FN / 4; k4++) {
            float4 f = xf[k4];
            #pragma unroll
            for (int j = 0; j < HD; j++) {
                t1[j] += f.x * sW1[(4 * k4 + 0) * HD + j];
                t1[j] += f.y * sW1[(4 * k4 + 1) * HD + j];
                t1[j] += f.z * sW1[(4 * k4 + 2) * HD + j];
                t1[j] += f.w * sW1[(4 * k4 + 3) * HD + j];
            }
        }
        float t2[HD];
        #pragma unroll
        for (int k = 0; k < HD; k++) t2[k] = sb2[k];
        #pragma unroll
        for (int j = 0; j < HD; j++) {
            float aj = fmaxf(t1[j], 0.f);
            #pragma unroll
            for (int k = 0; k < HD; k++) t2[k] += aj * sW2[j * HD + k];
        }
        sv = nfcb[0];
        #pragma unroll
        for (int k = 0; k < HD; k++) sv += fmaxf(t2[k], 0.f) * sw[k];
    }
    float bs = block_reduce_256(sv);
    if (threadIdx.x == 0) atomicAdd(&sums[b], (double)bs);
}

// ---------- col path: grid (4 col-blocks, 4 batches) ----------
__global__ void k_col(const float* __restrict__ col, const float* __restrict__ cW1,
                      const float* __restrict__ cb1, const float* __restrict__ cW2,
                      const float* __restrict__ cb2, double* __restrict__ sums) {
    __shared__ float sW1[FCOL * HD];
    __shared__ float sb1[HD], sw2[HD];
    for (int i = threadIdx.x; i < FCOL * HD; i += blockDim.x) sW1[i] = cW1[i];
    if (threadIdx.x < HD) { sb1[threadIdx.x] = cb1[threadIdx.x]; sw2[threadIdx.x] = cW2[threadIdx.x]; }
    __syncthreads();
    int b = blockIdx.y;
    int c = blockIdx.x * blockDim.x + threadIdx.x;
    float sv = 0.f;
    if (c < NC) {
        const float4* cf = (const float4*)(col + ((size_t)b * NC + c) * FCOL);
        float h[HD];
        #pragma unroll
        for (int j = 0; j < HD; j++) h[j] = sb1[j];
        #pragma unroll
        for (int k4 = 0; k4 < FCOL / 4; k4++) {
            float4 f = cf[k4];
            #pragma unroll
            for (int j = 0; j < HD; j++) {
                h[j] += f.x * sW1[(4 * k4 + 0) * HD + j];
                h[j] += f.y * sW1[(4 * k4 + 1) * HD + j];
                h[j] += f.z * sW1[(4 * k4 + 2) * HD + j];
                h[j] += f.w * sW1[(4 * k4 + 3) * HD + j];
            }
        }
        float co = cb2[0];
        #pragma unroll
        for (int j = 0; j < HD; j++) co += fmaxf(h[j], 0.f) * sw2[j];
        sv = co;
    }
    float bs = block_reduce_256(sv);
    if (threadIdx.x == 0) atomicAdd(&sums[4 + b], (double)bs);
}

// ---------- final tiny head ----------
__global__ void k_final(const double* __restrict__ sums,
                        const float* __restrict__ fcW, const float* __restrict__ fcb,
                        const float* __restrict__ outW, const float* __restrict__ outb,
                        float* __restrict__ out) {
    int b = threadIdx.x;
    if (b < NBAT) {
        float na = (float)(sums[b] * (1.0 / NN));
        float ca = (float)(sums[4 + b] * (1.0 / NC));
        float o = outb[0];
        #pragma unroll
        for (int j = 0; j < HD; j++) {
            float z = fmaxf(na * fcW[j] + ca * fcW[HD + j] + fcb[j], 0.f);
            o += z * outW[j];
        }
        out[b] = o;
    }
}

extern "C" void kernel_launch(void* const* d_in, const int* in_sizes, int n_in,
                              void* d_out, int out_size, void* d_ws, size_t ws_size,
                              hipStream_t stream) {
    const float* x    = (const float*)d_in[0];
    const float* col  = (const float*)d_in[1];
    const int*   ei   = (const int*)d_in[2];
    const float* W1   = (const float*)d_in[3];
    const float* b1   = (const float*)d_in[4];
    const float* W2   = (const float*)d_in[5];
    const float* b2   = (const float*)d_in[6];
    const float* nfcW = (const float*)d_in[7];
    const float* nfcb = (const float*)d_in[8];
    const float* cW1  = (const float*)d_in[9];
    const float* cb1  = (const float*)d_in[10];
    const float* cW2  = (const float*)d_in[11];
    const float* cb2  = (const float*)d_in[12];
    const float* fcW  = (const float*)d_in[13];
    const float* fcb  = (const float*)d_in[14];
    const float* outW = (const float*)d_in[15];
    const float* outb = (const float*)d_in[16];
    float* out = (float*)d_out;

    char* ws = (char*)d_ws;
    int*    cnt    = (int*)   (ws + 0);         // 50000 int
    int*    rowptr = (int*)   (ws + 200704);    // 50000 int
    float*  dinv   = (float*) (ws + 401408);    // 50000 f
    int*    cursor = (int*)   (ws + 602112);    // 50000 int
    int*    bsum   = (int*)   (ws + 802816);    // 64 int
    int*    csr    = (int*)   (ws + 803072);    // 1.6M int
    float*  y1     = (float*) (ws + 7203072);   // 800000 f
    float*  y2     = (float*) (ws + 10403072);  // 800000 f
    double* sums   = (double*)(ws + 13603072);  // 8 doubles

    const int* src = ei;
    const int* dst = ei + NE;

    hipMemsetAsync(cnt, 0, NN * sizeof(int), stream);
    hipMemsetAsync(cursor, 0, NN * sizeof(int), stream);
    hipMemsetAsync(sums, 0, 8 * sizeof(double), stream);

    k_count <<<(NE + 255) / 256, 256, 0, stream>>>(dst, cnt);
    k_scan1 <<<49, 256, 0, stream>>>(cnt, rowptr, bsum);
    k_scan2 <<<1, 64, 0, stream>>>(bsum);
    k_rowptr<<<(NN + 255) / 256, 256, 0, stream>>>(cnt, rowptr, bsum, dinv);
    k_fill  <<<(NE + 255) / 256, 256, 0, stream>>>(src, dst, rowptr, cursor, csr);

    k_xw1   <<<(NN + 255) / 256, 256, 0, stream>>>(x, W1, y1);
    k_conv1 <<<(NN + 15) / 16, 256, 0, stream>>>(rowptr, cnt, csr, dinv, y1, b1, W2, y2);
    k_conv2 <<<(NN + 15) / 16, 256, 0, stream>>>(rowptr, cnt, csr, dinv, y2, b2, nfcW, nfcb, sums);

    dim3 gmlp((NN + 255) / 256, NBAT - 1);
    k_mlp   <<<gmlp, 256, 0, stream>>>(x, W1, b1, W2, b2, nfcW, nfcb, sums);
    dim3 gcol((NC + 255) / 256, NBAT);
    k_col   <<<gcol, 256, 0, stream>>>(col, cW1, cb1, cW2, cb2, sums);
    k_final <<<1, 64, 0, stream>>>(sums, fcW, fcb, outW, outb, out);
}